// Round 1
// baseline (2215.653 us; speedup 1.0000x reference)
//
#include <hip/hip_runtime.h>
#include <stdint.h>

// ---------------------------------------------------------------------------
// E8RHTLinear: y = fwht(fwht(x*SV)/sqrt(N) @ W^T)/sqrt(M) * SU * Wscale
// Restructured: y = t @ V^T * (SU*Wscale), where
//   t = fwht(x*SV)/64   (bf16, ws)
//   V = fwht_cols(W_hat)/128  (bf16, ws, in-place 4-step FWHT along M)
// T=8192, N=4096, M=16384.
// ---------------------------------------------------------------------------

typedef __attribute__((ext_vector_type(8)))  __bf16 bf16x8;
typedef __attribute__((ext_vector_type(4)))  float  f32x4;
typedef __attribute__((ext_vector_type(4)))  unsigned short us4;

#define T_ROWS 8192
#define N_DIM  4096
#define M_DIM  16384

__device__ __forceinline__ unsigned short f2bf(float f) {
    unsigned int u = __float_as_uint(f);
    u = (u + 0x7FFFu + ((u >> 16) & 1u)) >> 16;   // RNE
    return (unsigned short)u;
}
__device__ __forceinline__ float bf2f(unsigned short h) {
    return __uint_as_float(((unsigned int)h) << 16);
}

__device__ __forceinline__ void g2l16(const void* g, void* l) {
    __builtin_amdgcn_global_load_lds(
        (const __attribute__((address_space(1))) void*)g,
        (__attribute__((address_space(3))) void*)l,
        16, 0, 0);
}

// ---------------------------------------------------------------------------
// Kernel 1: t[row] = bf16( fwht(x[row]*SV) / 64 )   one block per row
// ---------------------------------------------------------------------------
__global__ __launch_bounds__(256) void fwht_x_kernel(
    const float* __restrict__ x, const float* __restrict__ SV,
    unsigned short* __restrict__ t)
{
    __shared__ float s[N_DIM];
    const int row = blockIdx.x;
    const int tid = threadIdx.x;
    const float4* xv  = (const float4*)(x + (size_t)row * N_DIM);
    const float4* svv = (const float4*)SV;
#pragma unroll
    for (int q = 0; q < 4; ++q) {
        int u = tid + q * 256;
        float4 a = xv[u], b = svv[u];
        float4 r; r.x = a.x*b.x; r.y = a.y*b.y; r.z = a.z*b.z; r.w = a.w*b.w;
        *(float4*)&s[u * 4] = r;
    }
    __syncthreads();
    for (int h = 1; h < N_DIM; h <<= 1) {
#pragma unroll
        for (int k = 0; k < 8; ++k) {
            int p = tid + k * 256;
            int i = ((p & ~(h - 1)) << 1) | (p & (h - 1));
            float a = s[i], b = s[i + h];
            s[i] = a + b;
            s[i + h] = a - b;
        }
        __syncthreads();
    }
    const float sc = 1.0f / 64.0f;  // 1/sqrt(4096)
    us4* tv = (us4*)(t + (size_t)row * N_DIM);
#pragma unroll
    for (int q = 0; q < 4; ++q) {
        int u = tid + q * 256;
        us4 o;
        o.x = f2bf(s[u*4+0] * sc);
        o.y = f2bf(s[u*4+1] * sc);
        o.z = f2bf(s[u*4+2] * sc);
        o.w = f2bf(s[u*4+3] * sc);
        tv[u] = o;
    }
}

// ---------------------------------------------------------------------------
// Kernel 2: W1[m][n] = bf16( cb[Qidxs[m][n/8]][n%8] + irs*cb2[Qidxs2[...]][...] )
// one thread per index (8 outputs, 16B contiguous store)
// ---------------------------------------------------------------------------
__global__ __launch_bounds__(256) void decompress_kernel(
    const int* __restrict__ Qidxs, const int* __restrict__ Qidxs2,
    const float* __restrict__ cb, const float* __restrict__ cb2,
    const float* __restrict__ inv_resid_scale,
    unsigned short* __restrict__ W1)
{
    const size_t g = (size_t)blockIdx.x * 256 + threadIdx.x;  // 0 .. M*N/8
    const float irs = inv_resid_scale[0];
    int i1 = Qidxs[g], i2 = Qidxs2[g];
    const float4* c1 = (const float4*)(cb  + (size_t)i1 * 8);
    const float4* c2 = (const float4*)(cb2 + (size_t)i2 * 8);
    float4 a0 = c1[0], a1 = c1[1], b0 = c2[0], b1 = c2[1];
    us4 o0, o1;
    o0.x = f2bf(a0.x + irs * b0.x);
    o0.y = f2bf(a0.y + irs * b0.y);
    o0.z = f2bf(a0.z + irs * b0.z);
    o0.w = f2bf(a0.w + irs * b0.w);
    o1.x = f2bf(a1.x + irs * b1.x);
    o1.y = f2bf(a1.y + irs * b1.y);
    o1.z = f2bf(a1.z + irs * b1.z);
    o1.w = f2bf(a1.w + irs * b1.w);
    us4* out = (us4*)(W1 + g * 8);
    out[0] = o0;
    out[1] = o1;
}

// ---------------------------------------------------------------------------
// Kernel 3: in-place FWHT-128 along M over a 128(rows)x32(cols) tile.
//   pass1: rows = grp*128 + r          (rbase_mul=128, rstride=1,  scale=1)
//   pass2: rows = grp + 128*r          (rbase_mul=1,  rstride=128, scale=1/128)
// grid = (128 groups, 128 column tiles)
// ---------------------------------------------------------------------------
__global__ __launch_bounds__(256) void colfwht_kernel(
    unsigned short* __restrict__ W, int rbase_mul, int rstride, float scale)
{
    __shared__ float s[32 * 129];
    const int grp = blockIdx.x;
    const int n0  = blockIdx.y * 32;
    const int tid = threadIdx.x;
    const int base = grp * rbase_mul;

#pragma unroll
    for (int q = 0; q < 4; ++q) {
        int u = tid + q * 256;
        int r = u >> 3, cc = u & 7;
        size_t m = (size_t)(base + r * rstride);
        us4 v = *(const us4*)(W + m * N_DIM + n0 + cc * 4);
        s[(cc*4+0)*129 + r] = bf2f(v.x);
        s[(cc*4+1)*129 + r] = bf2f(v.y);
        s[(cc*4+2)*129 + r] = bf2f(v.z);
        s[(cc*4+3)*129 + r] = bf2f(v.w);
    }
    __syncthreads();
    for (int h = 1; h < 128; h <<= 1) {
#pragma unroll
        for (int k = 0; k < 8; ++k) {
            int g = tid + k * 256;
            int c = g >> 6, pr = g & 63;
            int i = ((pr & ~(h - 1)) << 1) | (pr & (h - 1));
            float* col = s + c * 129;
            float a = col[i], b = col[i + h];
            col[i] = a + b;
            col[i + h] = a - b;
        }
        __syncthreads();
    }
#pragma unroll
    for (int q = 0; q < 4; ++q) {
        int u = tid + q * 256;
        int r = u >> 3, cc = u & 7;
        size_t m = (size_t)(base + r * rstride);
        us4 o;
        o.x = f2bf(s[(cc*4+0)*129 + r] * scale);
        o.y = f2bf(s[(cc*4+1)*129 + r] * scale);
        o.z = f2bf(s[(cc*4+2)*129 + r] * scale);
        o.w = f2bf(s[(cc*4+3)*129 + r] * scale);
        *(us4*)(W + m * N_DIM + n0 + cc * 4) = o;
    }
}

// ---------------------------------------------------------------------------
// Kernel 4: GEMM  Y[i][j] = (SU[j]*Wscale) * sum_k t[i][k] * V[j][k]
// 128x128 block tile, BK=32, 4 waves (2x2), each wave 4x4 of 16x16x32 MFMA.
// global_load_lds width-16 staging (m97 structure).
// ---------------------------------------------------------------------------
__global__ __launch_bounds__(256) void gemm_kernel(
    const unsigned short* __restrict__ A,   // t: T_ROWS x N_DIM (bf16 bits)
    const unsigned short* __restrict__ B,   // V: M_DIM  x N_DIM (bf16 bits)
    const float* __restrict__ SU,
    const float* __restrict__ Wscale,
    float* __restrict__ Y)
{
    __shared__ unsigned short As[128 * 32];
    __shared__ unsigned short Bs[128 * 32];

    const int tid  = threadIdx.x;
    const int lane = tid & 63;
    const int w    = tid >> 6;
    const int wm   = w & 1;
    const int wn   = w >> 1;
    const int i0   = blockIdx.x * 128;
    const int j0   = blockIdx.y * 128;

    f32x4 acc[4][4] = {};

    const int lrow = lane >> 2;        // 0..15: row within 16-row chunk
    const int lc8  = (lane & 3) * 8;   // 0,8,16,24: k-offset

    for (int k0 = 0; k0 < N_DIM; k0 += 32) {
        __syncthreads();
#pragma unroll
        for (int q = 0; q < 2; ++q) {
            const int rr = w * 32 + q * 16;          // wave-uniform chunk base
            const unsigned short* ga =
                A + (size_t)(i0 + rr + lrow) * N_DIM + k0 + lc8;
            g2l16(ga, &As[rr * 32]);
            const unsigned short* gb =
                B + (size_t)(j0 + rr + lrow) * N_DIM + k0 + lc8;
            g2l16(gb, &Bs[rr * 32]);
        }
        __syncthreads();

        const int k8   = (lane >> 4) * 8;  // 0,8,16,24
        const int mrow = lane & 15;
        bf16x8 af[4], bfr[4];
#pragma unroll
        for (int tm = 0; tm < 4; ++tm)
            af[tm] = *(const bf16x8*)&As[(wm * 64 + tm * 16 + mrow) * 32 + k8];
#pragma unroll
        for (int tn = 0; tn < 4; ++tn)
            bfr[tn] = *(const bf16x8*)&Bs[(wn * 64 + tn * 16 + mrow) * 32 + k8];
#pragma unroll
        for (int tm = 0; tm < 4; ++tm)
#pragma unroll
            for (int tn = 0; tn < 4; ++tn)
                acc[tm][tn] = __builtin_amdgcn_mfma_f32_16x16x32_bf16(
                    af[tm], bfr[tn], acc[tm][tn], 0, 0, 0);
    }

    // epilogue: C/D layout col=lane&15, row=(lane>>4)*4+reg
    const float wsc  = Wscale[0];
    const int ccol  = lane & 15;
    const int crow4 = (lane >> 4) * 4;
#pragma unroll
    for (int tn = 0; tn < 4; ++tn) {
        const int col = j0 + wn * 64 + tn * 16 + ccol;
        const float su = SU[col] * wsc;
#pragma unroll
        for (int tm = 0; tm < 4; ++tm) {
            const int rowb = i0 + wm * 64 + tm * 16 + crow4;
#pragma unroll
            for (int r = 0; r < 4; ++r)
                Y[(size_t)(rowb + r) * M_DIM + col] = acc[tm][tn][r] * su;
        }
    }
}

// ---------------------------------------------------------------------------
extern "C" void kernel_launch(void* const* d_in, const int* in_sizes, int n_in,
                              void* d_out, int out_size, void* d_ws, size_t ws_size,
                              hipStream_t stream) {
    const float* x       = (const float*)d_in[0];
    const int*   Qidxs   = (const int*)  d_in[1];
    const int*   Qidxs2  = (const int*)  d_in[2];
    const float* SU      = (const float*)d_in[3];
    const float* SV      = (const float*)d_in[4];
    const float* cb      = (const float*)d_in[5];
    const float* cb2     = (const float*)d_in[6];
    const float* Wscale  = (const float*)d_in[7];
    const float* irs     = (const float*)d_in[8];
    float*       y       = (float*)d_out;

    char* ws = (char*)d_ws;
    unsigned short* t  = (unsigned short*)ws;                        // 64 MB
    unsigned short* W1 = (unsigned short*)(ws + ((size_t)64 << 20)); // 128 MB

    // t = fwht(x*SV)/64
    fwht_x_kernel<<<T_ROWS, 256, 0, stream>>>(x, SV, t);
    // W1 = decompressed W_hat (bf16)
    decompress_kernel<<<(M_DIM * (N_DIM / 8)) / 256, 256, 0, stream>>>(
        Qidxs, Qidxs2, cb, cb2, irs, W1);
    // V = fwht(W1 along M)/128, in-place, 4-step: FWHT128(contig) then FWHT128(stride 128)
    colfwht_kernel<<<dim3(128, N_DIM / 32), 256, 0, stream>>>(W1, 128, 1, 1.0f);
    colfwht_kernel<<<dim3(128, N_DIM / 32), 256, 0, stream>>>(W1, 1, 128, 1.0f / 128.0f);
    // y = t @ V^T * SU * Wscale
    gemm_kernel<<<dim3(T_ROWS / 128, M_DIM / 128), 256, 0, stream>>>(
        t, W1, SU, Wscale, y);
}